// Round 7
// baseline (37.879 us; speedup 1.0000x reference)
//
#include <hip/hip_runtime.h>

#define HH 64
#define WW 64
#define TT 16
#define NPIX (HH * WW * TT)   // 65536

// lane i <- lane i-1 within 16-lane DPP rows (row_shr:1), 0-fill at row start.
__device__ __forceinline__ float dpp_up1(float x) {
    return __int_as_float(__builtin_amdgcn_update_dpp(
        0, __float_as_int(x), 0x111, 0xF, 0xF, true));
}
// lane i <- lane i+1 within 16-lane DPP rows (row_shl:1), 0-fill at row end.
__device__ __forceinline__ float dpp_dn1(float x) {
    return __int_as_float(__builtin_amdgcn_update_dpp(
        0, __float_as_int(x), 0x101, 0xF, 0xF, true));
}

// Round-6 skeleton (512 blocks x 8 waves = 16 waves/CU, K=2 t-blocking,
// DPP t-halo, L2-resident by construction) + software pipelining:
//   - 9 guidance channels double-buffered in registers, prefetched 1 column
//     ahead (latency hidden under ~700cy of column compute)
//   - est/var/img for the CURRENT column issued at column start (consumed
//     250..550cy later)
// Column loop fully unrolled (7 slots); all buffers statically indexed.
__global__ __launch_bounds__(512) void statdenoise_kernel(
    const float* __restrict__ img,
    const float* __restrict__ gui,
    const float* __restrict__ est,
    const float* __restrict__ var,
    float* __restrict__ out)
{
    const float SIG[9] = {0.1f, 0.1f, 0.1f, 50.0f, 50.0f, 50.0f, 10.0f, 10.0f, 10.0f};
    const float G2 = 2.907f * 2.907f;   // gamma^2

    const int lane = threadIdx.x & 63;
    const int s    = threadIdx.x >> 6;          // wave id == column-split 0..7
    const int tg   = lane & 7;                  // t-group 0..7
    const int hwl  = lane >> 3;                 // 0..7
    const int hw   = blockIdx.x * 8 + hwl;      // 8 consecutive (h,w) per block
    const int h    = hw >> 6;                   // block-uniform
    const int w    = hw & 63;
    const int t0   = tg * 2;                    // owns t0, t0+1
    const int cpx  = hw * 16 + t0;

    // center values (float2 along t)
    float2 gc[9];
#pragma unroll
    for (int c = 0; c < 9; ++c) gc[c] = *(const float2*)&gui[c * NPIX + cpx];
    float2 ec[3], vc[3];
#pragma unroll
    for (int c = 0; c < 3; ++c) {
        ec[c] = *(const float2*)&est[c * NPIX + cpx];
        vc[c] = *(const float2*)&var[c * NPIX + cpx];
    }

    const bool vLo = (t0 != 0);    // dt=-1 for e=0; also masks DPP boundary garbage
    const bool vHi = (t0 != 14);   // dt=+1 for e=1; also masks DPP boundary garbage

    float acc[2][4] = {};   // per owned t: {r,g,b,wsum}

    // ---- slot-0 column state (column r = s + 8*i) ----
    int dh = s / 7 - 3, dw = s % 7 - 3;
    int hh = h + dh, ww = w + dw;
    bool hhOK  = (unsigned)hh < (unsigned)HH;
    bool colOK = (unsigned)ww < (unsigned)WW;
    int off = (((min(max(hh, 0), HH - 1) << 6) + min(max(ww, 0), WW - 1)) << 4) + t0;

    float2 gA[9], gB[9];
#pragma unroll
    for (int c = 0; c < 9; ++c) gA[c] = *(const float2*)&gui[c * NPIX + off];

#pragma unroll
    for (int i = 0; i < 7; ++i) {
        float2 (&cur)[9] = (i & 1) ? gB : gA;   // compile-time (loop unrolled)
        float2 (&nxt)[9] = (i & 1) ? gA : gB;

        // next slot's coordinates (clamped address: always safe to prefetch)
        int dhn = dh, dwn = dw + 8;
        while (dwn > 3) { dwn -= 7; ++dhn; }
        const int hhn = h + dhn, wwn = w + dwn;
        const bool hhOKn  = (unsigned)hhn < (unsigned)HH;
        const bool colOKn = (unsigned)wwn < (unsigned)WW;
        const int offn =
            (((min(max(hhn, 0), HH - 1) << 6) + min(max(wwn, 0), WW - 1)) << 4) + t0;

        // prefetch next column's guidance (9 x float2)
        if (i < 6) {
#pragma unroll
            for (int c = 0; c < 9; ++c) nxt[c] = *(const float2*)&gui[c * NPIX + offn];
        }

        // current column's est/var/img: issue now, consumed 250..550cy later
        float2 em[3], vm[3], im[3];
#pragma unroll
        for (int c = 0; c < 3; ++c) {
            em[c] = *(const float2*)&est[c * NPIX + off];
            vm[c] = *(const float2*)&var[c * NPIX + off];
            im[c] = *(const float2*)&img[c * NPIX + off];
        }

        const bool valid = ((s + 8 * i) < 49) && hhOK;   // wave-uniform
        if (valid) {
            // ---- bilateral over 9 guidance channels, 6 (e,dt) pairs ----
            float sb[2][3] = {};
#pragma unroll
            for (int c = 0; c < 9; ++c) {
                float2 m = cur[c];
                float nv[4] = {dpp_up1(m.y), m.x, m.y, dpp_dn1(m.x)};  // t0-1..t0+2
#pragma unroll
                for (int e = 0; e < 2; ++e) {
                    float ce = e ? gc[c].y : gc[c].x;
#pragma unroll
                    for (int k = 0; k < 3; ++k) {
                        float d = ce - nv[e + k];
                        sb[e][k] = fmaf(d * d, SIG[c], sb[e][k]);
                    }
                }
            }

            // ---- membership (division-free Welch t-test) ----
            // (OOB h/w neighbors provably get weight 0 in the reference, so
            //  skipping them is exact; center pair passes naturally: d2==0.)
            bool mem[2][3] = {{true, true, true}, {true, true, true}};
#pragma unroll
            for (int c = 0; c < 3; ++c) {
                float env[4] = {dpp_up1(em[c].y), em[c].x, em[c].y, dpp_dn1(em[c].x)};
                float vnv[4] = {dpp_up1(vm[c].y), vm[c].x, vm[c].y, dpp_dn1(vm[c].x)};
#pragma unroll
                for (int e = 0; e < 2; ++e) {
                    float ece = e ? ec[c].y : ec[c].x;
                    float vce = e ? vc[c].y : vc[c].x;
#pragma unroll
                    for (int k = 0; k < 3; ++k) {
                        float d  = ece - env[e + k];
                        float d2 = d * d;
                        float V  = vce + vnv[e + k];
                        bool pass = (d2 < G2 * V) | ((d2 == 0.f) & (V == 0.f));
                        bool kill = ((vce == 0.f) | (vnv[e + k] == 0.f)) & (d2 != 0.f);
                        mem[e][k] = mem[e][k] & pass & (!kill);
                    }
                }
            }

            // ---- weights ----
            float wt[2][3];
#pragma unroll
            for (int e = 0; e < 2; ++e) {
#pragma unroll
                for (int k = 0; k < 3; ++k) {
                    bool ok = colOK && mem[e][k];
                    if (e == 0 && k == 0) ok = ok && vLo;   // tt = t0-1
                    if (e == 1 && k == 2) ok = ok && vHi;   // tt = t0+2
                    wt[e][k] = ok ? __expf(-0.5f * sb[e][k]) : 0.f;
                }
            }

            // ---- accumulate image ----
#pragma unroll
            for (int c = 0; c < 3; ++c) {
                float iv[4] = {dpp_up1(im[c].y), im[c].x, im[c].y, dpp_dn1(im[c].x)};
#pragma unroll
                for (int e = 0; e < 2; ++e) {
                    acc[e][c] = fmaf(wt[e][0], iv[e],
                                fmaf(wt[e][1], iv[e + 1],
                                fmaf(wt[e][2], iv[e + 2], acc[e][c])));
                }
            }
#pragma unroll
            for (int e = 0; e < 2; ++e)
                acc[e][3] += wt[e][0] + wt[e][1] + wt[e][2];
        }

        // advance column state
        dh = dhn; dw = dwn; hh = hhn; ww = wwn;
        hhOK = hhOKn; colOK = colOKn; off = offn;
    }

    // ---- combine the 8 splits through LDS ----
    __shared__ float4 red[2][8][64];
    red[0][s][lane] = make_float4(acc[0][0], acc[0][1], acc[0][2], acc[0][3]);
    red[1][s][lane] = make_float4(acc[1][0], acc[1][1], acc[1][2], acc[1][3]);
    __syncthreads();

    if (threadIdx.x < 128) {
        const int j = threadIdx.x;
        const int l = j >> 1, e = j & 1;
        float4 sum = red[e][0][l];
#pragma unroll
        for (int q = 1; q < 8; ++q) {
            float4 v = red[e][q][l];
            sum.x += v.x; sum.y += v.y; sum.z += v.z; sum.w += v.w;
        }
        const int px = blockIdx.x * 128 + j;   // px_local == j by construction
        const float inv = 1.f / sum.w;         // wsum >= 1 (center weight == 1)
        out[0 * NPIX + px] = sum.x * inv;
        out[1 * NPIX + px] = sum.y * inv;
        out[2 * NPIX + px] = sum.z * inv;
    }
}

extern "C" void kernel_launch(void* const* d_in, const int* in_sizes, int n_in,
                              void* d_out, int out_size, void* d_ws, size_t ws_size,
                              hipStream_t stream) {
    const float* img = (const float*)d_in[0];
    const float* gui = (const float*)d_in[1];
    const float* est = (const float*)d_in[2];
    const float* var = (const float*)d_in[3];
    float* out = (float*)d_out;

    dim3 grid(4096 / 8);    // 512 blocks: 8 (h,w) x 16 t pixels, 8 splits each
    dim3 block(512);
    statdenoise_kernel<<<grid, block, 0, stream>>>(img, gui, est, var, out);
}